// Round 2
// baseline (205.239 us; speedup 1.0000x reference)
//
#include <hip/hip_runtime.h>
#include <math.h>

#define N_NODES 100000
#define N_EDGES 1600000

#define NB_SHIFT 7
#define NB 128                                    // nodes per bin
#define NBINS 782                                 // ceil(N_NODES/128)
#define RCAP 2432                                 // per-bin sorted cap: lambda=2046, +8.5 sigma
#define BCHUNK 4096                               // edges per binning block
#define BINBLOCKS ((N_EDGES + BCHUNK - 1) / BCHUNK)   // 391
#define LCAP 16                                   // chunk cap = one 64B line (lambda=5.2)
#define SPB 8                                     // per-block deterministic spill cap

// pack two f32 into one uint of two bf16 (RNE); unpack halves
__device__ __forceinline__ unsigned int pack_bf2(float a, float b) {
    unsigned int ua = __float_as_uint(a), ub = __float_as_uint(b);
    ua += 0x7FFFu + ((ua >> 16) & 1u);
    ub += 0x7FFFu + ((ub >> 16) & 1u);
    return (ua >> 16) | (ub & 0xFFFF0000u);
}
__device__ __forceinline__ float bf_lo(unsigned int u) { return __uint_as_float(u << 16); }
__device__ __forceinline__ float bf_hi(unsigned int u) { return __uint_as_float(u & 0xFFFF0000u); }

#define QR(v) { v += __shfl_xor(v, 1, 64); v += __shfl_xor(v, 2, 64); }

// ---------------- binning + global degree histogram + xbf pack ----------------
// record = (src << 7) | (dst & 127); log[block][bin][16] full-line chunks;
// cnt_tab gates validity; deterministic per-block spill list.
// NEW vs baseline: atomicAdd degree per edge (deg pre-zeroed by memsetAsync);
// xbf[node] = uint4 of 8 bf16(x) — unscaled, so it needs no degrees.
__global__ __launch_bounds__(512) void k_bin(const int* __restrict__ src, const int* __restrict__ dst,
                                             const float* __restrict__ x,
                                             int* __restrict__ cnt_tab, int* __restrict__ log,
                                             int* __restrict__ spill_rec, int* __restrict__ spill_bin,
                                             int* __restrict__ deg, unsigned int* __restrict__ xbf, int e) {
    __shared__ int lcnt[NBINS];
    __shared__ int lbuf[NBINS * LCAP];
    __shared__ int sp_rec[SPB];
    __shared__ int sp_bin[SPB];
    __shared__ int sp_n;
    int tid = threadIdx.x, blk = blockIdx.x;
    // xbf pack: 391*512 = 200192 threads >= 100000 nodes, one node each (no LDS dep)
    {
        int node = blk * 512 + tid;
        if (node < N_NODES) {
            const float4* x4 = (const float4*)x;
            float4 xa = x4[node * 2], xb = x4[node * 2 + 1];
            uint4 u;
            u.x = pack_bf2(xa.x, xa.y); u.y = pack_bf2(xa.z, xa.w);
            u.z = pack_bf2(xb.x, xb.y); u.w = pack_bf2(xb.z, xb.w);
            ((uint4*)xbf)[node] = u;
        }
    }
    for (int b = tid; b < NBINS; b += 512) lcnt[b] = 0;
    if (tid == 0) sp_n = 0;
    __syncthreads();
    int base = blk * BCHUNK;
    int end = min(base + BCHUNK, e);
    for (int i = base + tid; i < end; i += 512) {
        int d = dst[i], s = src[i];
        atomicAdd(&deg[d], 1);                    // global in-degree histogram (L2-hot)
        int b = d >> NB_SHIFT;
        int rec = (s << NB_SHIFT) | (d & (NB - 1));
        int slot = atomicAdd(&lcnt[b], 1);
        if (slot < LCAP) {
            lbuf[b * LCAP + slot] = rec;
        } else {                                  // rare bucket overflow -> LDS spill list
            int k = atomicAdd(&sp_n, 1);
            if (k < SPB) { sp_rec[k] = rec; sp_bin[k] = b; }
        }
    }
    __syncthreads();
    for (int b = tid; b < NBINS; b += 512) cnt_tab[blk * NBINS + b] = min(lcnt[b], LCAP);
    int* lrow = log + blk * NBINS * LCAP;
    for (int idx = tid; idx < NBINS * LCAP; idx += 512) lrow[idx] = lbuf[idx];
    if (tid < SPB) {
        int valid = tid < min(sp_n, SPB);
        spill_rec[blk * SPB + tid] = valid ? sp_rec[tid] : 0;
        spill_bin[blk * SPB + tid] = valid ? sp_bin[tid] : -1;   // -1 sentinel
    }
}

// ---------------- fused: compaction + counting sort + dinv + layer-1 agg + MLP ----------------
// Builds the bin's CSR in LDS and consumes it in-place (no gxu round-trip, no
// regions/row_start re-read for layer 1). Still writes regions/row_start/gcur/dinv
// for the final kernel. Gather side: xbf[s] (16B) + deg[s] (4B) + rsqrtf per edge.
__global__ __launch_bounds__(512, 4) void k_sort_agg1(const int* __restrict__ cnt_tab, const int* __restrict__ log,
                                                      const int* __restrict__ spill_rec, const int* __restrict__ spill_bin,
                                                      int* __restrict__ gcur, int* __restrict__ regions,
                                                      int* __restrict__ row_start, float* __restrict__ dinv,
                                                      const unsigned int* __restrict__ xbf, const int* __restrict__ deg,
                                                      const float* __restrict__ W1, const float* __restrict__ b1,
                                                      const float* __restrict__ W2,
                                                      unsigned int* __restrict__ g2u) {
    __shared__ int ccnt[BINBLOCKS];
    __shared__ int coff[BINBLOCKS];
    __shared__ int wtot[8];
    __shared__ int msum_s;
    __shared__ int sp_take;
    __shared__ int lrec[RCAP];                    // sort scratch; reused as weight cache after scatter
    __shared__ int lsort[RCAP];
    __shared__ int cnt[NB];
    __shared__ int stt[NB];
    __shared__ int cur[NB];
    __shared__ float di_s[NB];
    int b = blockIdx.x, tid = threadIdx.x;
    int lane = tid & 63, wv = tid >> 6;

    // 1. load this bin's count column; zero histogram
    for (int c = tid; c < BINBLOCKS; c += 512) ccnt[c] = cnt_tab[c * NBINS + b];
    if (tid == 0) sp_take = 0;
    if (tid < NB) cnt[tid] = 0;
    __syncthreads();
    // 2. block exclusive scan of 391 counts
    int v = (tid < BINBLOCKS) ? ccnt[tid] : 0;
    int s = v;
#pragma unroll
    for (int off = 1; off < 64; off <<= 1) {
        int t = __shfl_up(s, off, 64);
        if (lane >= off) s += t;
    }
    if (lane == 63) wtot[wv] = s;
    __syncthreads();
    if (tid == 0) {
        int acc = 0;
#pragma unroll
        for (int w = 0; w < 8; ++w) { int t = wtot[w]; wtot[w] = acc; acc += t; }
        msum_s = acc;
    }
    __syncthreads();
    if (tid < BINBLOCKS) coff[tid] = (s - v) + wtot[wv];
    __syncthreads();
    // 3. compact valid chunk prefixes into lrec, histogram inline
    for (int idx = tid; idx < BINBLOCKS * LCAP; idx += 512) {
        int c = idx >> 4, k = idx & (LCAP - 1);
        if (k < ccnt[c]) {
            int pos = coff[c] + k;
            if (pos < RCAP) {
                int rec = log[(c * NBINS + b) * LCAP + k];
                lrec[pos] = rec;
                atomicAdd(&cnt[rec & (NB - 1)], 1);
            }
        }
    }
    // 4. merge spills belonging to this bin, histogram inline
    for (int jj = tid; jj < BINBLOCKS * SPB; jj += 512) {
        if (spill_bin[jj] == b) {
            int p = atomicAdd(&sp_take, 1);
            int pos = msum_s + p;
            if (pos < RCAP) {
                int rec = spill_rec[jj];
                lrec[pos] = rec;
                atomicAdd(&cnt[rec & (NB - 1)], 1);
            }
        }
    }
    __syncthreads();
    int m = min(msum_s + sp_take, RCAP);
    if (tid == 0) gcur[b] = m;
    if (tid < 64) {                               // wave0: exclusive scan of 128 counts
        int c0 = cnt[lane], c1 = cnt[64 + lane];
        int s0 = c0, s1 = c1;
#pragma unroll
        for (int off = 1; off < 64; off <<= 1) {
            int t0 = __shfl_up(s0, off, 64);
            int t1 = __shfl_up(s1, off, 64);
            if (lane >= off) { s0 += t0; s1 += t1; }
        }
        s1 += __shfl(s0, 63, 64);
        stt[lane] = s0 - c0;
        stt[64 + lane] = s1 - c1;
    }
    __syncthreads();
    int node0 = b << NB_SHIFT;
    if (tid < NB) {
        cur[tid] = stt[tid];
        float d = rsqrtf((float)cnt[tid] + 1.0f);
        di_s[tid] = d;
        row_start[b * NB + tid] = b * RCAP + stt[tid];
        int node = node0 + tid;
        if (node < N_NODES) dinv[node] = d;
    }
    __syncthreads();
    for (int j = tid; j < m; j += 512) {          // counting-sort scatter (LDS int atomic)
        int rec = lrec[j];
        int pos = atomicAdd(&cur[rec & (NB - 1)], 1);
        lsort[pos] = rec >> NB_SHIFT;
    }
    __syncthreads();
    // 5. write-back CSR for the final kernel; stage weights into dead lrec region
    int* wb = regions + b * RCAP;
    for (int j = tid; j < m; j += 512) wb[j] = lsort[j];
    float* wsh = (float*)lrec;                    // [0,256)=W1  [256,288)=b1  [288,800)=W2
    for (int i = tid; i < 800; i += 512)
        wsh[i] = (i < 256) ? W1[i] : (i < 288) ? b1[i - 256] : W2[i - 288];
    __syncthreads();

    // 6. layer-1 aggregation + MLP; 4 lanes/node, CSR from LDS
    {
        int l = tid >> 2, q = tid & 3;
        int node = node0 + l;
        if (node < N_NODES) {
            int js = stt[l];
            int je = (l < NB - 1) ? stt[l + 1] : m;
            const uint4* xb4 = (const uint4*)xbf;
            float a0 = 0.f, a1 = 0.f, a2 = 0.f, a3 = 0.f, a4 = 0.f, a5 = 0.f, a6 = 0.f, a7 = 0.f;
            if (q == 0) {                         // self term: x[i]*dinv[i]
                uint4 u = xb4[node];
                float d = di_s[l];
                a0 = bf_lo(u.x) * d; a1 = bf_hi(u.x) * d; a2 = bf_lo(u.y) * d; a3 = bf_hi(u.y) * d;
                a4 = bf_lo(u.z) * d; a5 = bf_hi(u.z) * d; a6 = bf_lo(u.w) * d; a7 = bf_hi(u.w) * d;
            }
            for (int j = js + q; j < je; j += 4) {  // quad-strided gather: xbf[s]*dinv[s]
                int sx = lsort[j];
                uint4 u = xb4[sx];
                float w = rsqrtf((float)deg[sx] + 1.0f);
                a0 = fmaf(bf_lo(u.x), w, a0); a1 = fmaf(bf_hi(u.x), w, a1);
                a2 = fmaf(bf_lo(u.y), w, a2); a3 = fmaf(bf_hi(u.y), w, a3);
                a4 = fmaf(bf_lo(u.z), w, a4); a5 = fmaf(bf_hi(u.z), w, a5);
                a6 = fmaf(bf_lo(u.w), w, a6); a7 = fmaf(bf_hi(u.w), w, a7);
            }
            QR(a0); QR(a1); QR(a2); QR(a3); QR(a4); QR(a5); QR(a6); QR(a7);
            float di = di_s[l];
            float y[8] = { a0 * di, a1 * di, a2 * di, a3 * di, a4 * di, a5 * di, a6 * di, a7 * di };
            const float* W1s = wsh;
            const float* b1s = wsh + 256;
            const float* W2s = wsh + 288;
            float hh[8];
#pragma unroll
            for (int ff = 0; ff < 8; ++ff) {
                int f = q * 8 + ff;
                float sa = b1s[f];
#pragma unroll
                for (int k = 0; k < 8; ++k) sa = fmaf(y[k], W1s[k * 32 + f], sa);
                hh[ff] = fmaxf(0.f, sa);
            }
            float g[16];
#pragma unroll
            for (int o = 0; o < 16; ++o) {
                float sa = 0.f;
#pragma unroll
                for (int ff = 0; ff < 8; ++ff) sa = fmaf(hh[ff], W2s[(q * 8 + ff) * 16 + o], sa);
                g[o] = sa;
            }
#pragma unroll
            for (int o = 0; o < 16; ++o) QR(g[o]);
            int f0 = q * 4;
            uint2 pk = make_uint2(pack_bf2(g[f0] * di, g[f0 + 1] * di),
                                  pack_bf2(g[f0 + 2] * di, g[f0 + 3] * di));
            ((uint2*)g2u)[node * 4 + q] = pk;
        }
    }
}

// ---------------- layer-2 aggregation + fused FC/sigmoid; 4 lanes/node ----------------
__global__ __launch_bounds__(256) void k_agg2_final(const int* __restrict__ gcur, const int* __restrict__ regions,
                                                    const int* __restrict__ row_start,
                                                    const unsigned int* __restrict__ g2u,
                                                    const float* __restrict__ dinv,
                                                    const float* __restrict__ b2, const float* __restrict__ Wfc,
                                                    const float* __restrict__ bfc, float* __restrict__ out) {
    int t = blockIdx.x * blockDim.x + threadIdx.x;
    int i = t >> 2;
    if (i >= N_NODES) return;
    int q = t & 3;
    int b = i >> NB_SHIFT, l = i & (NB - 1);
    int js = row_start[i];
    int je = (l < NB - 1) ? row_start[i + 1] : b * RCAP + gcur[b];
    const uint4* g24 = (const uint4*)g2u;
    float a[16];
#pragma unroll
    for (int f = 0; f < 16; ++f) a[f] = 0.f;
    if (q == 0) {
        uint4 u0 = g24[i * 2], u1 = g24[i * 2 + 1];
        a[0] = bf_lo(u0.x); a[1] = bf_hi(u0.x); a[2] = bf_lo(u0.y); a[3] = bf_hi(u0.y);
        a[4] = bf_lo(u0.z); a[5] = bf_hi(u0.z); a[6] = bf_lo(u0.w); a[7] = bf_hi(u0.w);
        a[8] = bf_lo(u1.x); a[9] = bf_hi(u1.x); a[10] = bf_lo(u1.y); a[11] = bf_hi(u1.y);
        a[12] = bf_lo(u1.z); a[13] = bf_hi(u1.z); a[14] = bf_lo(u1.w); a[15] = bf_hi(u1.w);
    }
    for (int j = js + q; j < je; j += 4) {
        int s = regions[j];
        uint4 u0 = g24[s * 2], u1 = g24[s * 2 + 1];
        a[0] += bf_lo(u0.x); a[1] += bf_hi(u0.x); a[2] += bf_lo(u0.y); a[3] += bf_hi(u0.y);
        a[4] += bf_lo(u0.z); a[5] += bf_hi(u0.z); a[6] += bf_lo(u0.w); a[7] += bf_hi(u0.w);
        a[8] += bf_lo(u1.x); a[9] += bf_hi(u1.x); a[10] += bf_lo(u1.y); a[11] += bf_hi(u1.y);
        a[12] += bf_lo(u1.z); a[13] += bf_hi(u1.z); a[14] += bf_lo(u1.w); a[15] += bf_hi(u1.w);
    }
#pragma unroll
    for (int f = 0; f < 16; ++f) {
        a[f] += __shfl_xor(a[f], 1, 64);
        a[f] += __shfl_xor(a[f], 2, 64);
    }
    if (q == 0) {
        float di = dinv[i];
        float z = bfc[0];
#pragma unroll
        for (int f = 0; f < 16; ++f)
            z += fmaxf(0.f, di * a[f] + b2[f]) * Wfc[f];
        out[i] = 1.0f / (1.0f + expf(-z));
    }
}

extern "C" void kernel_launch(void* const* d_in, const int* in_sizes, int n_in,
                              void* d_out, int out_size, void* d_ws, size_t ws_size,
                              hipStream_t stream) {
    const float* x   = (const float*)d_in[0];
    const int*   ei  = (const int*)d_in[1];
    const float* W1  = (const float*)d_in[2];
    const float* b1  = (const float*)d_in[3];
    const float* W2  = (const float*)d_in[4];
    const float* b2  = (const float*)d_in[5];
    const float* Wfc = (const float*)d_in[6];
    const float* bfc = (const float*)d_in[7];
    float* out = (float*)d_out;

    const int* src = ei;
    const int* dst = ei + N_EDGES;
    const int N = N_NODES, E = N_EDGES;

    // workspace (4B elems):
    //   cnt_tab 391*782 | log 391*782*16 | spill_rec/bin 391*8 | gcur 782 |
    //   regions 782*2432 | row_start 782*128 | deg N | dinv N | xbf 4N | g2u 8N  (~34.5 MB)
    int*          cnt_tab   = (int*)d_ws;
    int*          log       = cnt_tab + BINBLOCKS * NBINS;
    int*          spill_rec = log + BINBLOCKS * NBINS * LCAP;
    int*          spill_bin = spill_rec + BINBLOCKS * SPB;
    int*          gcur      = spill_bin + BINBLOCKS * SPB;
    int*          regions   = gcur + NBINS;
    int*          row_start = regions + NBINS * RCAP;
    int*          deg       = row_start + NBINS * NB;
    float*        dinv      = (float*)(deg + N);
    unsigned int* xbf       = (unsigned int*)(dinv + N);
    unsigned int* g2u       = xbf + (size_t)N * 4;

    auto grid = [](int work, int blk) { return (work + blk - 1) / blk; };

    hipMemsetAsync(deg, 0, (size_t)N * sizeof(int), stream);
    k_bin<<<BINBLOCKS, 512, 0, stream>>>(src, dst, x, cnt_tab, log, spill_rec, spill_bin, deg, xbf, E);
    k_sort_agg1<<<NBINS, 512, 0, stream>>>(cnt_tab, log, spill_rec, spill_bin, gcur, regions, row_start,
                                           dinv, xbf, deg, W1, b1, W2, g2u);
    k_agg2_final<<<grid(N * 4, 256), 256, 0, stream>>>(gcur, regions, row_start, g2u, dinv, b2, Wfc, bfc, out);
}

// Round 3
// 144.684 us; speedup vs baseline: 1.4185x; 1.4185x over previous
//
#include <hip/hip_runtime.h>
#include <math.h>

#define N_NODES 100000
#define N_EDGES 1600000

#define NB_SHIFT 7
#define NB 128                                    // nodes per bin
#define NBINS 782                                 // ceil(N_NODES/128)
#define RCAP 2432                                 // per-bin sorted cap: lambda=2046, +8.5 sigma
#define BCHUNK 2048                               // edges per binning block
#define BINBLOCKS ((N_EDGES + BCHUNK - 1) / BCHUNK)   // 782
#define LCAP 8                                    // per-(block,bin) chunk cap; lambda = 2.62
#define SPB 16                                    // per-block spill cap; E[spills] ~= 1.6

// pack two f32 into one uint of two bf16 (RNE); unpack halves
__device__ __forceinline__ unsigned int pack_bf2(float a, float b) {
    unsigned int ua = __float_as_uint(a), ub = __float_as_uint(b);
    ua += 0x7FFFu + ((ua >> 16) & 1u);
    ub += 0x7FFFu + ((ub >> 16) & 1u);
    return (ua >> 16) | (ub & 0xFFFF0000u);
}
__device__ __forceinline__ float bf_lo(unsigned int u) { return __uint_as_float(u << 16); }
__device__ __forceinline__ float bf_hi(unsigned int u) { return __uint_as_float(u & 0xFFFF0000u); }

#define QR(v) { v += __shfl_xor(v, 1, 64); v += __shfl_xor(v, 2, 64); }

// ---------------- binning: record = (src << 7) | (dst & 127) ----------------
// 782 blocks x 2048 edges (vs 391x4096): 2x grid for latency hiding, 28 KB LDS.
// Conditional log write: only valid slots (lambda 2.62 of 8) -> ~1/3 the write bytes.
__global__ __launch_bounds__(512) void k_bin(const int* __restrict__ src, const int* __restrict__ dst,
                                             unsigned char* __restrict__ cnt_tab, int* __restrict__ log,
                                             int* __restrict__ spill_rec, int* __restrict__ spill_bin, int e) {
    __shared__ int lcnt[NBINS];
    __shared__ int lbuf[NBINS * LCAP];
    __shared__ int sp_rec[SPB];
    __shared__ int sp_bin[SPB];
    __shared__ int sp_n;
    int tid = threadIdx.x, blk = blockIdx.x;
    for (int b = tid; b < NBINS; b += 512) lcnt[b] = 0;
    if (tid == 0) sp_n = 0;
    __syncthreads();
    int base = blk * BCHUNK;
    int end = min(base + BCHUNK, e);
    for (int i = base + tid; i < end; i += 512) {
        int d = dst[i], s = src[i];
        int b = d >> NB_SHIFT;
        int rec = (s << NB_SHIFT) | (d & (NB - 1));
        int slot = atomicAdd(&lcnt[b], 1);
        if (slot < LCAP) {
            lbuf[b * LCAP + slot] = rec;
        } else {                                  // rare bucket overflow -> LDS spill list
            int k = atomicAdd(&sp_n, 1);
            if (k < SPB) { sp_rec[k] = rec; sp_bin[k] = b; }
        }
    }
    __syncthreads();
    for (int b = tid; b < NBINS; b += 512) cnt_tab[blk * NBINS + b] = (unsigned char)min(lcnt[b], LCAP);
    int* lrow = log + blk * NBINS * LCAP;
    for (int idx = tid; idx < NBINS * LCAP; idx += 512) {
        int c = idx >> 3;
        if ((idx & (LCAP - 1)) < lcnt[c]) lrow[idx] = lbuf[idx];
    }
    if (tid < SPB) {
        int valid = tid < min(sp_n, SPB);
        spill_rec[blk * SPB + tid] = valid ? sp_rec[tid] : 0;
        spill_bin[blk * SPB + tid] = valid ? sp_bin[tid] : -1;   // -1 sentinel
    }
}

// ---------------- compaction(+histogram) + counting sort + dinv + gx (block per bin) ----------------
__global__ __launch_bounds__(512) void k_sort(const unsigned char* __restrict__ cnt_tab, const int* __restrict__ log,
                                              const int* __restrict__ spill_rec, const int* __restrict__ spill_bin,
                                              int* __restrict__ gcur, int* __restrict__ regions,
                                              const float* __restrict__ x, float* __restrict__ dinv,
                                              unsigned int* __restrict__ gxu, int* __restrict__ row_start) {
    __shared__ int ccnt[BINBLOCKS];
    __shared__ int coff[BINBLOCKS];
    __shared__ int wtot[8];
    __shared__ int msum_s;
    __shared__ int sp_take;
    __shared__ int lrec[RCAP];
    __shared__ int lsort[RCAP];
    __shared__ int cnt[NB];
    __shared__ int stt[NB];
    __shared__ int cur[NB];
    __shared__ float di_s[NB];
    int b = blockIdx.x, tid = threadIdx.x;
    int lane = tid & 63, wv = tid >> 6;

    // 1. load this bin's count column; zero histogram
    for (int c = tid; c < BINBLOCKS; c += 512) ccnt[c] = cnt_tab[c * NBINS + b];
    if (tid == 0) sp_take = 0;
    if (tid < NB) cnt[tid] = 0;
    __syncthreads();
    // 2. block exclusive scan of 782 counts, two per thread
    {
        int c0 = tid * 2, c1 = c0 + 1;
        int v0 = (c0 < BINBLOCKS) ? ccnt[c0] : 0;
        int v1 = (c1 < BINBLOCKS) ? ccnt[c1] : 0;
        int v = v0 + v1, sc = v;
#pragma unroll
        for (int off = 1; off < 64; off <<= 1) {
            int t = __shfl_up(sc, off, 64);
            if (lane >= off) sc += t;
        }
        if (lane == 63) wtot[wv] = sc;
        __syncthreads();
        if (tid == 0) {
            int acc = 0;
#pragma unroll
            for (int w = 0; w < 8; ++w) { int t = wtot[w]; wtot[w] = acc; acc += t; }
            msum_s = acc;
        }
        __syncthreads();
        int basep = sc - v + wtot[wv];
        if (c0 < BINBLOCKS) coff[c0] = basep;
        if (c1 < BINBLOCKS) coff[c1] = basep + v0;
    }
    __syncthreads();
    // 3. compact valid chunk prefixes into lrec, histogram inline
    for (int idx = tid; idx < BINBLOCKS * LCAP; idx += 512) {
        int c = idx >> 3, k = idx & (LCAP - 1);
        if (k < ccnt[c]) {
            int pos = coff[c] + k;
            if (pos < RCAP) {
                int rec = log[(c * NBINS + b) * LCAP + k];
                lrec[pos] = rec;
                atomicAdd(&cnt[rec & (NB - 1)], 1);
            }
        }
    }
    // 4. merge spills belonging to this bin, histogram inline
    for (int jj = tid; jj < BINBLOCKS * SPB; jj += 512) {
        if (spill_bin[jj] == b) {
            int p = atomicAdd(&sp_take, 1);
            int pos = msum_s + p;
            if (pos < RCAP) {
                int rec = spill_rec[jj];
                lrec[pos] = rec;
                atomicAdd(&cnt[rec & (NB - 1)], 1);
            }
        }
    }
    __syncthreads();
    int m = min(msum_s + sp_take, RCAP);
    if (tid == 0) gcur[b] = m;
    if (tid < 64) {                               // wave0: exclusive scan of 128 counts
        int c0 = cnt[lane], c1 = cnt[64 + lane];
        int s0 = c0, s1 = c1;
#pragma unroll
        for (int off = 1; off < 64; off <<= 1) {
            int t0 = __shfl_up(s0, off, 64);
            int t1 = __shfl_up(s1, off, 64);
            if (lane >= off) { s0 += t0; s1 += t1; }
        }
        s1 += __shfl(s0, 63, 64);
        stt[lane] = s0 - c0;
        stt[64 + lane] = s1 - c1;
    }
    __syncthreads();
    int node0 = b << NB_SHIFT;
    if (tid < NB) {
        cur[tid] = stt[tid];
        float d = rsqrtf((float)cnt[tid] + 1.0f);
        di_s[tid] = d;
        row_start[b * NB + tid] = b * RCAP + stt[tid];
        int node = node0 + tid;
        if (node < N_NODES) dinv[node] = d;
    }
    __syncthreads();
    {   // gx = bf16(x * dinv): 128 nodes x 4 float2 = 512 threads exactly
        int l = tid >> 2, p = tid & 3;
        int node = node0 + l;
        if (node < N_NODES) {
            const float2* x2 = (const float2*)x;
            float2 xv = x2[node * 4 + p];
            float d = di_s[l];
            gxu[node * 4 + p] = pack_bf2(xv.x * d, xv.y * d);
        }
    }
    for (int j = tid; j < m; j += 512) {          // counting-sort scatter (LDS int atomic)
        int rec = lrec[j];
        int pos = atomicAdd(&cur[rec & (NB - 1)], 1);
        lsort[pos] = rec >> NB_SHIFT;
    }
    __syncthreads();
    int* wb = regions + b * RCAP;
    for (int j = tid; j < m; j += 512) wb[j] = lsort[j];   // coalesced write-back
}

// ---------------- layer-1 aggregation + MLP; bin-per-block, CSR staged in LDS ----------------
__global__ __launch_bounds__(512) void k_agg1_mlp(const int* __restrict__ gcur, const int* __restrict__ regions,
                                                  const int* __restrict__ row_start,
                                                  const unsigned int* __restrict__ gxu,
                                                  const float* __restrict__ dinv,
                                                  const float* __restrict__ W1, const float* __restrict__ b1,
                                                  const float* __restrict__ W2,
                                                  unsigned int* __restrict__ g2u) {
    __shared__ int lsort[RCAP];
    __shared__ float wsh[800];                    // [0,256)=W1  [256,288)=b1  [288,800)=W2
    int b = blockIdx.x, tid = threadIdx.x;
    int m = gcur[b];
    const int* rrow = regions + b * RCAP;
    for (int j = tid; j < m; j += 512) lsort[j] = rrow[j];
    for (int i2 = tid; i2 < 800; i2 += 512)
        wsh[i2] = (i2 < 256) ? W1[i2] : (i2 < 288) ? b1[i2 - 256] : W2[i2 - 288];
    __syncthreads();
    int l = tid >> 2, q = tid & 3;
    int node = (b << NB_SHIFT) + l;
    if (node >= N_NODES) return;
    int js = row_start[node] - b * RCAP;
    int je = (l < NB - 1) ? (row_start[node + 1] - b * RCAP) : m;
    const uint4* gx4 = (const uint4*)gxu;
    float a0 = 0.f, a1 = 0.f, a2 = 0.f, a3 = 0.f, a4 = 0.f, a5 = 0.f, a6 = 0.f, a7 = 0.f;
    if (q == 0) {                                 // self term on lane 0
        uint4 u = gx4[node];
        a0 = bf_lo(u.x); a1 = bf_hi(u.x); a2 = bf_lo(u.y); a3 = bf_hi(u.y);
        a4 = bf_lo(u.z); a5 = bf_hi(u.z); a6 = bf_lo(u.w); a7 = bf_hi(u.w);
    }
    int j = js + q;
    for (; j + 4 < je; j += 8) {                  // 2-deep unroll: 2 gathers in flight
        int s0 = lsort[j], s1 = lsort[j + 4];
        uint4 u = gx4[s0];
        uint4 w = gx4[s1];
        a0 += bf_lo(u.x); a1 += bf_hi(u.x); a2 += bf_lo(u.y); a3 += bf_hi(u.y);
        a4 += bf_lo(u.z); a5 += bf_hi(u.z); a6 += bf_lo(u.w); a7 += bf_hi(u.w);
        a0 += bf_lo(w.x); a1 += bf_hi(w.x); a2 += bf_lo(w.y); a3 += bf_hi(w.y);
        a4 += bf_lo(w.z); a5 += bf_hi(w.z); a6 += bf_lo(w.w); a7 += bf_hi(w.w);
    }
    if (j < je) {
        uint4 u = gx4[lsort[j]];
        a0 += bf_lo(u.x); a1 += bf_hi(u.x); a2 += bf_lo(u.y); a3 += bf_hi(u.y);
        a4 += bf_lo(u.z); a5 += bf_hi(u.z); a6 += bf_lo(u.w); a7 += bf_hi(u.w);
    }
    QR(a0); QR(a1); QR(a2); QR(a3); QR(a4); QR(a5); QR(a6); QR(a7);
    float di = dinv[node];
    float y[8] = { a0 * di, a1 * di, a2 * di, a3 * di, a4 * di, a5 * di, a6 * di, a7 * di };
    const float* W1s = wsh;
    const float* b1s = wsh + 256;
    const float* W2s = wsh + 288;
    float hh[8];
#pragma unroll
    for (int ff = 0; ff < 8; ++ff) {
        int f = q * 8 + ff;
        float sa = b1s[f];
#pragma unroll
        for (int k = 0; k < 8; ++k) sa = fmaf(y[k], W1s[k * 32 + f], sa);
        hh[ff] = fmaxf(0.f, sa);
    }
    float g[16];
#pragma unroll
    for (int o = 0; o < 16; ++o) {
        float sa = 0.f;
#pragma unroll
        for (int ff = 0; ff < 8; ++ff) sa = fmaf(hh[ff], W2s[(q * 8 + ff) * 16 + o], sa);
        g[o] = sa;
    }
#pragma unroll
    for (int o = 0; o < 16; ++o) QR(g[o]);
    int f0 = q * 4;
    uint2 pk = make_uint2(pack_bf2(g[f0] * di, g[f0 + 1] * di),
                          pack_bf2(g[f0 + 2] * di, g[f0 + 3] * di));
    ((uint2*)g2u)[node * 4 + q] = pk;
}

// ---------------- layer-2 aggregation + fused FC/sigmoid; bin-per-block ----------------
__global__ __launch_bounds__(512) void k_agg2_final(const int* __restrict__ gcur, const int* __restrict__ regions,
                                                    const int* __restrict__ row_start,
                                                    const unsigned int* __restrict__ g2u,
                                                    const float* __restrict__ dinv,
                                                    const float* __restrict__ b2, const float* __restrict__ Wfc,
                                                    const float* __restrict__ bfc, float* __restrict__ out) {
    __shared__ int lsort[RCAP];
    int b = blockIdx.x, tid = threadIdx.x;
    int m = gcur[b];
    const int* rrow = regions + b * RCAP;
    for (int j = tid; j < m; j += 512) lsort[j] = rrow[j];
    __syncthreads();
    int l = tid >> 2, q = tid & 3;
    int node = (b << NB_SHIFT) + l;
    if (node >= N_NODES) return;
    int js = row_start[node] - b * RCAP;
    int je = (l < NB - 1) ? (row_start[node + 1] - b * RCAP) : m;
    const uint4* g24 = (const uint4*)g2u;
    float a[16];
#pragma unroll
    for (int f = 0; f < 16; ++f) a[f] = 0.f;
    if (q == 0) {
        uint4 u0 = g24[node * 2], u1 = g24[node * 2 + 1];
        a[0] = bf_lo(u0.x); a[1] = bf_hi(u0.x); a[2] = bf_lo(u0.y); a[3] = bf_hi(u0.y);
        a[4] = bf_lo(u0.z); a[5] = bf_hi(u0.z); a[6] = bf_lo(u0.w); a[7] = bf_hi(u0.w);
        a[8] = bf_lo(u1.x); a[9] = bf_hi(u1.x); a[10] = bf_lo(u1.y); a[11] = bf_hi(u1.y);
        a[12] = bf_lo(u1.z); a[13] = bf_hi(u1.z); a[14] = bf_lo(u1.w); a[15] = bf_hi(u1.w);
    }
    int j = js + q;
    for (; j + 4 < je; j += 8) {                  // 2-deep unroll: 4 gathers in flight
        int s0 = lsort[j], s1 = lsort[j + 4];
        uint4 u0 = g24[s0 * 2], u1 = g24[s0 * 2 + 1];
        uint4 w0 = g24[s1 * 2], w1 = g24[s1 * 2 + 1];
        a[0] += bf_lo(u0.x); a[1] += bf_hi(u0.x); a[2] += bf_lo(u0.y); a[3] += bf_hi(u0.y);
        a[4] += bf_lo(u0.z); a[5] += bf_hi(u0.z); a[6] += bf_lo(u0.w); a[7] += bf_hi(u0.w);
        a[8] += bf_lo(u1.x); a[9] += bf_hi(u1.x); a[10] += bf_lo(u1.y); a[11] += bf_hi(u1.y);
        a[12] += bf_lo(u1.z); a[13] += bf_hi(u1.z); a[14] += bf_lo(u1.w); a[15] += bf_hi(u1.w);
        a[0] += bf_lo(w0.x); a[1] += bf_hi(w0.x); a[2] += bf_lo(w0.y); a[3] += bf_hi(w0.y);
        a[4] += bf_lo(w0.z); a[5] += bf_hi(w0.z); a[6] += bf_lo(w0.w); a[7] += bf_hi(w0.w);
        a[8] += bf_lo(w1.x); a[9] += bf_hi(w1.x); a[10] += bf_lo(w1.y); a[11] += bf_hi(w1.y);
        a[12] += bf_lo(w1.z); a[13] += bf_hi(w1.z); a[14] += bf_lo(w1.w); a[15] += bf_hi(w1.w);
    }
    if (j < je) {
        int s0 = lsort[j];
        uint4 u0 = g24[s0 * 2], u1 = g24[s0 * 2 + 1];
        a[0] += bf_lo(u0.x); a[1] += bf_hi(u0.x); a[2] += bf_lo(u0.y); a[3] += bf_hi(u0.y);
        a[4] += bf_lo(u0.z); a[5] += bf_hi(u0.z); a[6] += bf_lo(u0.w); a[7] += bf_hi(u0.w);
        a[8] += bf_lo(u1.x); a[9] += bf_hi(u1.x); a[10] += bf_lo(u1.y); a[11] += bf_hi(u1.y);
        a[12] += bf_lo(u1.z); a[13] += bf_hi(u1.z); a[14] += bf_lo(u1.w); a[15] += bf_hi(u1.w);
    }
#pragma unroll
    for (int f = 0; f < 16; ++f) QR(a[f]);
    if (q == 0) {
        float di = dinv[node];
        float z = bfc[0];
#pragma unroll
        for (int f = 0; f < 16; ++f)
            z += fmaxf(0.f, di * a[f] + b2[f]) * Wfc[f];
        out[node] = 1.0f / (1.0f + expf(-z));
    }
}

extern "C" void kernel_launch(void* const* d_in, const int* in_sizes, int n_in,
                              void* d_out, int out_size, void* d_ws, size_t ws_size,
                              hipStream_t stream) {
    const float* x   = (const float*)d_in[0];
    const int*   ei  = (const int*)d_in[1];
    const float* W1  = (const float*)d_in[2];
    const float* b1  = (const float*)d_in[3];
    const float* W2  = (const float*)d_in[4];
    const float* b2  = (const float*)d_in[5];
    const float* Wfc = (const float*)d_in[6];
    const float* bfc = (const float*)d_in[7];
    float* out = (float*)d_out;

    const int* src = ei;
    const int* dst = ei + N_EDGES;
    const int E = N_EDGES;

    // workspace (4B elems unless noted):
    //   log 782*782*8 (19.6MB) | spill_rec/bin 782*16 | gcur 782 | regions 782*2432 (7.6MB) |
    //   row_start 782*128 | dinv N | gxu 4N | g2u 8N | cnt_tab 782*782 BYTES (0.6MB)  (~33.5MB)
    int*           log       = (int*)d_ws;
    int*           spill_rec = log + (size_t)BINBLOCKS * NBINS * LCAP;
    int*           spill_bin = spill_rec + BINBLOCKS * SPB;
    int*           gcur      = spill_bin + BINBLOCKS * SPB;
    int*           regions   = gcur + NBINS;
    int*           row_start = regions + NBINS * RCAP;
    float*         dinv      = (float*)(row_start + NBINS * NB);
    unsigned int*  gxu       = (unsigned int*)(dinv + N_NODES);
    unsigned int*  g2u       = gxu + (size_t)N_NODES * 4;
    unsigned char* cnt_tab   = (unsigned char*)(g2u + (size_t)N_NODES * 8);

    k_bin<<<BINBLOCKS, 512, 0, stream>>>(src, dst, cnt_tab, log, spill_rec, spill_bin, E);
    k_sort<<<NBINS, 512, 0, stream>>>(cnt_tab, log, spill_rec, spill_bin, gcur, regions, x, dinv, gxu, row_start);
    k_agg1_mlp<<<NBINS, 512, 0, stream>>>(gcur, regions, row_start, gxu, dinv, W1, b1, W2, g2u);
    k_agg2_final<<<NBINS, 512, 0, stream>>>(gcur, regions, row_start, g2u, dinv, b2, Wfc, bfc, out);
}